// Round 17
// baseline (80.217 us; speedup 1.0000x reference)
//
#include <hip/hip_runtime.h>
#include <math.h>

#define kB 4
#define kM 4096
#define kN (kB * kM)
#define kPadF -999.0f
#define kPadI -999

#define kNC   11                    // cells per axis; 80/11 = 7.27 > CUTOFF
#define kNC3  (kNC * kNC * kNC)     // 1331 cells per batch
#define kCap  64                    // atoms per cell (realistic max ~15)
// d_ws layout (bytes):
#define kOffWs     0                            // float4[kN]      = 256 KB
#define kOffCnt    262144                       // int[kB*kNC3]    = 21 KB
#define kOffCells  524288                       // float4[kB*kNC3*kCap] = 5.45 MB
#define kWsNeeded  (kOffCells + (size_t)kB * kNC3 * kCap * 16)

// numpy-mimicking squared norm: (x*x + y*y) + z*z, all round-to-nearest.
__device__ __forceinline__ float sq_np(float x, float y, float z) {
    return __fadd_rn(__fadd_rn(__fmul_rn(x, x), __fmul_rn(y, y)),
                     __fmul_rn(z, z));
}

// raw v_sqrt_f32 (<=1 ulp). Mask is decided by the exact d2<=49 compare.
__device__ __forceinline__ float fast_sqrt(float x) {
#if __has_builtin(__builtin_amdgcn_sqrtf)
    return __builtin_amdgcn_sqrtf(x);
#else
    float r;
    asm volatile("v_sqrt_f32 %0, %1" : "=v"(r) : "v"(x));
    return r;
#endif
}

__device__ __forceinline__ int cell_coord(float v) {
    int c = (int)(v * (11.0f / 80.0f));
    return min(c, kNC - 1);
}

// ---------------------------------------------------------------------------
// Kernel 1 (role-split, R15): 64K threads, 4 independent roles x 16K rows.
//   role 0: gather -> ws + cell-bin (atomic slot)
//   role 1: dihedral -> out col0
//   role 2: partner0 -> out cols 2,3,4
//   role 3: partner1 -> out cols 5,6,7
// col 1 is fully owned by nbr_cell (plain store, R16) — no init here.
// ---------------------------------------------------------------------------
__global__ __launch_bounds__(256)
void per_atom_kernel(const float* __restrict__ coords,   // (B,M,3)
                     const int*   __restrict__ cidx,     // (N,)
                     const int*   __restrict__ partners, // (N,2)
                     const int*   __restrict__ aidx,     // (N,4)
                     float*       __restrict__ out,      // (N,8)
                     float4*      __restrict__ ws,       // gathered rows
                     int*         __restrict__ cellCnt,  // (B*1331,) zeroed
                     float4*      __restrict__ cells)    // (B*1331*kCap,)
{
    int role = blockIdx.x >> 6;                 // 64 blocks per role
    int i    = ((blockIdx.x & 63) << 8) + threadIdx.x;   // 0..16383
    int b    = i >> 12;

    if (role == 0) {
        int gc = cidx[i];
        const float* s = coords + (size_t)(b * kM + gc) * 3;
        float x = s[0], y = s[1], z = s[2];
        float4 v = make_float4(x, y, z, sq_np(x, y, z));
        ws[i] = v;
        if (x != kPadF) {
            int cid = ((b * kNC + cell_coord(x)) * kNC + cell_coord(y)) * kNC
                      + cell_coord(z);
            int slot = atomicAdd(&cellCnt[cid], 1);
            if (slot < kCap) cells[(size_t)cid * kCap + slot] = v;
        }
    } else if (role == 1) {
        int4 a = *reinterpret_cast<const int4*>(aidx + 4 * i);
        float ang = kPadF;
        if (a.x != kPadI && a.y != kPadI && a.z != kPadI && a.w != kPadI) {
            int ai[4] = {a.x, a.y, a.z, a.w};
            float P[4][3];
            #pragma unroll
            for (int k = 0; k < 4; ++k) {
                int g  = ai[k];
                int gb = g >> 12;
                int gc = cidx[g];
                const float* s = coords + (size_t)(gb * kM + gc) * 3;
                P[k][0] = s[0]; P[k][1] = s[1]; P[k][2] = s[2];
            }
            float b1x = P[1][0] - P[0][0], b1y = P[1][1] - P[0][1], b1z = P[1][2] - P[0][2];
            float b2x = P[2][0] - P[1][0], b2y = P[2][1] - P[1][1], b2z = P[2][2] - P[1][2];
            float b3x = P[3][0] - P[2][0], b3y = P[3][1] - P[2][1], b3z = P[3][2] - P[2][2];
            float n1x = b1y * b2z - b1z * b2y;
            float n1y = b1z * b2x - b1x * b2z;
            float n1z = b1x * b2y - b1y * b2x;
            float n2x = b2y * b3z - b2z * b3y;
            float n2y = b2z * b3x - b2x * b3z;
            float n2z = b2x * b3y - b2y * b3x;
            float nb2 = sqrtf(b2x * b2x + b2y * b2y + b2z * b2z) + 1e-12f;
            float inv = 1.0f / nb2;
            float ux = b2x * inv, uy = b2y * inv, uz = b2z * inv;
            float m1x = n1y * uz - n1z * uy;
            float m1y = n1z * ux - n1x * uz;
            float m1z = n1x * uy - n1y * ux;
            float x = n1x * n2x + n1y * n2y + n1z * n2z;
            float y = m1x * n2x + m1y * n2y + m1z * n2z;
            ang = atan2f(y, x);
        }
        out[(size_t)i * 8 + 0] = ang;
    } else if (role == 2) {
        float o2, o3, o4;
        int p0 = partners[2 * i + 0];
        if (p0 == kPadI) { o2 = o3 = o4 = kPadF; }
        else {
            const float* s = coords + (size_t)(b * kM + p0) * 3;
            o2 = s[0]; o3 = s[1]; o4 = s[2];
        }
        float* o = out + (size_t)i * 8;
        o[2] = o2; o[3] = o3; o[4] = o4;
    } else {
        float o5, o6, o7;
        int p1 = partners[2 * i + 1];
        if (p1 == kPadI) { o5 = o6 = o7 = kPadF; }
        else {
            const float* s = coords + (size_t)(b * kM + p1) * 3;
            o5 = s[0]; o6 = s[1]; o7 = s[2];
        }
        float* o = out + (size_t)i * 8;
        o[5] = o5; o[6] = o6; o[7] = o7;
    }
}

// ---------------------------------------------------------------------------
// Kernel 2 (R16): CELL-LIST nbr sums, ATOMIC-FREE. 4 lanes per row; lane
// sub scans cells k = sub*7 .. (7/7/7/6 split of the 27-cell window), quad
// __shfl_xor reduce, lane 0 plain-stores the row sum (sole writer of col 1;
// pad rows store 0). Per-candidate numerics identical to R13/R14/R15
// (gram d2 via fma(-2,dot,sqi+sqj), exact d2<=49 mask, v_sqrt(|d2|));
// only summation order differs (positive terms, ~1e-5 vs threshold 20).
// ---------------------------------------------------------------------------
__global__ __launch_bounds__(256)
void nbr_cell_kernel(const float4* __restrict__ ws,      // (N,) x,y,z,sq
                     const int*    __restrict__ cellCnt, // (B*1331,)
                     const float4* __restrict__ cells,   // (B*1331*kCap,)
                     float*        __restrict__ out)     // (N,8)
{
    int t   = blockIdx.x * 256 + threadIdx.x;   // 0 .. 4*kN-1
    int i   = t >> 2;                           // row
    int sub = t & 3;                            // lane within quad

    float4 ri = ws[i];
    bool valid = (ri.x != kPadF);

    float sum = 0.0f;
    if (valid) {
        int b  = i >> 12;
        int cx = cell_coord(ri.x), cy = cell_coord(ri.y), cz = cell_coord(ri.z);
        int k0 = sub * 7;
        int k1 = (sub < 3) ? k0 + 7 : 27;       // 7/7/7/6
        for (int k = k0; k < k1; ++k) {
            int nx = cx + (k / 9)       - 1;
            int ny = cy + ((k / 3) % 3) - 1;
            int nz = cz + (k % 3)       - 1;
            if ((unsigned)nx >= kNC || (unsigned)ny >= kNC || (unsigned)nz >= kNC)
                continue;
            int cid = ((b * kNC + nx) * kNC + ny) * kNC + nz;
            int cnt = min(cellCnt[cid], kCap);
            const float4* cp = cells + (size_t)cid * kCap;
            for (int s = 0; s < cnt; ++s) {
                float4 c   = cp[s];
                float dot  = __fmaf_rn(ri.z, c.z,
                             __fmaf_rn(ri.y, c.y, __fmul_rn(ri.x, c.x)));
                float d2   = __fmaf_rn(-2.0f, dot, __fadd_rn(ri.w, c.w));
                float dist = fast_sqrt(__builtin_fabsf(d2));
                sum += (d2 <= 49.0f) ? dist : 0.0f;
            }
        }
    }
    // quad reduce (lanes i*4 .. i*4+3 hold the same row)
    sum += __shfl_xor(sum, 1);
    sum += __shfl_xor(sum, 2);
    if (sub == 0) {
        out[(size_t)i * 8 + 1] = valid ? sum : 0.0f;   // sole writer, no atomic
    }
}

// ---------------------------------------------------------------------------
// Fallbacks (ws too small): monolithic per-atom + LDS-staged O(M^2) nbr.
// ---------------------------------------------------------------------------
__global__ __launch_bounds__(64)
void per_atom_mono_kernel(const float* __restrict__ coords,
                          const int*   __restrict__ cidx,
                          const int*   __restrict__ partners,
                          const int*   __restrict__ aidx,
                          float*       __restrict__ out)
{
    int i = blockIdx.x * 64 + threadIdx.x;
    if (i >= kN) return;
    int b = i >> 12;

    float o2, o3, o4, o5, o6, o7;
    int p0 = partners[2 * i + 0];
    int p1 = partners[2 * i + 1];
    if (p0 == kPadI) { o2 = o3 = o4 = kPadF; }
    else {
        const float* s = coords + (size_t)(b * kM + p0) * 3;
        o2 = s[0]; o3 = s[1]; o4 = s[2];
    }
    if (p1 == kPadI) { o5 = o6 = o7 = kPadF; }
    else {
        const float* s = coords + (size_t)(b * kM + p1) * 3;
        o5 = s[0]; o6 = s[1]; o7 = s[2];
    }

    int4 a = *reinterpret_cast<const int4*>(aidx + 4 * i);
    float ang = kPadF;
    if (a.x != kPadI && a.y != kPadI && a.z != kPadI && a.w != kPadI) {
        int ai[4] = {a.x, a.y, a.z, a.w};
        float P[4][3];
        #pragma unroll
        for (int k = 0; k < 4; ++k) {
            int g  = ai[k];
            int gb = g >> 12;
            int gc = cidx[g];
            const float* s = coords + (size_t)(gb * kM + gc) * 3;
            P[k][0] = s[0]; P[k][1] = s[1]; P[k][2] = s[2];
        }
        float b1x = P[1][0] - P[0][0], b1y = P[1][1] - P[0][1], b1z = P[1][2] - P[0][2];
        float b2x = P[2][0] - P[1][0], b2y = P[2][1] - P[1][1], b2z = P[2][2] - P[1][2];
        float b3x = P[3][0] - P[2][0], b3y = P[3][1] - P[2][1], b3z = P[3][2] - P[2][2];
        float n1x = b1y * b2z - b1z * b2y;
        float n1y = b1z * b2x - b1x * b2z;
        float n1z = b1x * b2y - b1y * b2x;
        float n2x = b2y * b3z - b2z * b3y;
        float n2y = b2z * b3x - b2x * b3z;
        float n2z = b2x * b3y - b2y * b3x;
        float nb2 = sqrtf(b2x * b2x + b2y * b2y + b2z * b2z) + 1e-12f;
        float inv = 1.0f / nb2;
        float ux = b2x * inv, uy = b2y * inv, uz = b2z * inv;
        float m1x = n1y * uz - n1z * uy;
        float m1y = n1z * ux - n1x * uz;
        float m1z = n1x * uy - n1y * ux;
        float x = n1x * n2x + n1y * n2y + n1z * n2z;
        float y = m1x * n2x + m1y * n2y + m1z * n2z;
        ang = atan2f(y, x);
    }

    float4* o = reinterpret_cast<float4*>(out + (size_t)i * 8);
    o[0] = make_float4(ang, 0.0f, o2, o3);
    o[1] = make_float4(o4, o5, o6, o7);
}

__global__ __launch_bounds__(256)
void nbr_kernel_lds(const float* __restrict__ coords,
                    const int*   __restrict__ cidx,
                    float*       __restrict__ out)
{
    __shared__ float4 sc[kM];
    int b    = blockIdx.x >> 6;
    int row0 = (blockIdx.x & 63) << 6;
    for (int j = threadIdx.x; j < kM; j += 256) {
        int idx = cidx[b * kM + j];
        const float* s = coords + (size_t)(b * kM + idx) * 3;
        float x = s[0], y = s[1], z = s[2];
        sc[j] = make_float4(x, y, z, sq_np(x, y, z));
    }
    __syncthreads();
    int r   = row0 + (threadIdx.x >> 2);
    int sub = threadIdx.x & 3;
    float4 ci = sc[r];
    float sum = 0.0f;
    for (int jj = 0; jj < kM / 4; ++jj) {
        float4 c   = sc[4 * jj + sub];
        float dot  = __fmaf_rn(ci.z, c.z,
                     __fmaf_rn(ci.y, c.y, __fmul_rn(ci.x, c.x)));
        float d2   = __fmaf_rn(-2.0f, dot, __fadd_rn(ci.w, c.w));
        float dist = fast_sqrt(fmaxf(d2, 0.0f));
        sum += (d2 <= 49.0f) ? dist : 0.0f;
    }
    sum += __shfl_xor(sum, 1);
    sum += __shfl_xor(sum, 2);
    if (sub == 0)
        out[(size_t)(b * kM + r) * 8 + 1] = (ci.x != kPadF) ? sum : 0.0f;
}

// ---------------------------------------------------------------------------
extern "C" void kernel_launch(void* const* d_in, const int* in_sizes, int n_in,
                              void* d_out, int out_size, void* d_ws, size_t ws_size,
                              hipStream_t stream) {
    const float* coords   = (const float*)d_in[0];
    const int*   cidx     = (const int*)d_in[2];
    const int*   partners = (const int*)d_in[3];
    const int*   aidx     = (const int*)d_in[4];
    float*       out      = (float*)d_out;

    char*   wsB     = (char*)d_ws;
    float4* ws      = (float4*)(wsB + kOffWs);
    int*    cellCnt = (int*)(wsB + kOffCnt);
    float4* cells   = (float4*)(wsB + kOffCells);

    if (ws_size >= kWsNeeded) {
        hipMemsetAsync(cellCnt, 0, (size_t)kB * kNC3 * sizeof(int), stream);
        hipLaunchKernelGGL(per_atom_kernel, dim3(256), dim3(256), 0, stream,
                           coords, cidx, partners, aidx, out, ws, cellCnt, cells);
        hipLaunchKernelGGL(nbr_cell_kernel, dim3((4 * kN) / 256), dim3(256),
                           0, stream, ws, cellCnt, cells, out);
    } else {
        hipLaunchKernelGGL(per_atom_mono_kernel, dim3(kN / 64), dim3(64), 0, stream,
                           coords, cidx, partners, aidx, out);
        hipLaunchKernelGGL(nbr_kernel_lds, dim3(kB * 64), dim3(256), 0, stream,
                           coords, cidx, out);
    }
}

// Round 18
// 74.340 us; speedup vs baseline: 1.0791x; 1.0791x over previous
//
#include <hip/hip_runtime.h>
#include <math.h>

#define kB 4
#define kM 4096
#define kN (kB * kM)
#define kPadF -999.0f
#define kPadI -999

#define kNC   11                    // cells per axis; 80/11 = 7.27 > CUTOFF
#define kNC3  (kNC * kNC * kNC)     // 1331 cells per batch
#define kCap  64                    // atoms per cell (realistic max ~15)
// d_ws layout (bytes):
#define kOffWs     0                            // float4[kN]      = 256 KB
#define kOffCnt    262144                       // int[kB*kNC3]    = 21 KB
#define kOffCells  524288                       // float4[kB*kNC3*kCap] = 5.45 MB
#define kWsNeeded  (kOffCells + (size_t)kB * kNC3 * kCap * 16)

// numpy-mimicking squared norm: (x*x + y*y) + z*z, all round-to-nearest.
__device__ __forceinline__ float sq_np(float x, float y, float z) {
    return __fadd_rn(__fadd_rn(__fmul_rn(x, x), __fmul_rn(y, y)),
                     __fmul_rn(z, z));
}

// raw v_sqrt_f32 (<=1 ulp). Mask is decided by the exact d2<=49 compare.
__device__ __forceinline__ float fast_sqrt(float x) {
#if __has_builtin(__builtin_amdgcn_sqrtf)
    return __builtin_amdgcn_sqrtf(x);
#else
    float r;
    asm volatile("v_sqrt_f32 %0, %1" : "=v"(r) : "v"(x));
    return r;
#endif
}

__device__ __forceinline__ int cell_coord(float v) {
    int c = (int)(v * (11.0f / 80.0f));
    return min(c, kNC - 1);
}

// ---------------------------------------------------------------------------
// Kernel 1 (role-split, R15 config): 64K threads, 4 roles x 16K rows.
//   role 0: gather -> ws + cell-bin (atomic slot) + out col1 = 0
//   role 1: dihedral -> out col0
//   role 2: partner0 -> out cols 2,3,4
//   role 3: partner1 -> out cols 5,6,7
// Disjoint output columns -> no write conflicts.
// ---------------------------------------------------------------------------
__global__ __launch_bounds__(256)
void per_atom_kernel(const float* __restrict__ coords,   // (B,M,3)
                     const int*   __restrict__ cidx,     // (N,)
                     const int*   __restrict__ partners, // (N,2)
                     const int*   __restrict__ aidx,     // (N,4)
                     float*       __restrict__ out,      // (N,8)
                     float4*      __restrict__ ws,       // gathered rows
                     int*         __restrict__ cellCnt,  // (B*1331,) zeroed
                     float4*      __restrict__ cells)    // (B*1331*kCap,)
{
    int role = blockIdx.x >> 6;                 // 64 blocks per role
    int i    = ((blockIdx.x & 63) << 8) + threadIdx.x;   // 0..16383
    int b    = i >> 12;

    if (role == 0) {
        int gc = cidx[i];
        const float* s = coords + (size_t)(b * kM + gc) * 3;
        float x = s[0], y = s[1], z = s[2];
        float4 v = make_float4(x, y, z, sq_np(x, y, z));
        ws[i] = v;
        out[(size_t)i * 8 + 1] = 0.0f;
        if (x != kPadF) {
            int cid = ((b * kNC + cell_coord(x)) * kNC + cell_coord(y)) * kNC
                      + cell_coord(z);
            int slot = atomicAdd(&cellCnt[cid], 1);
            if (slot < kCap) cells[(size_t)cid * kCap + slot] = v;
        }
    } else if (role == 1) {
        int4 a = *reinterpret_cast<const int4*>(aidx + 4 * i);
        float ang = kPadF;
        if (a.x != kPadI && a.y != kPadI && a.z != kPadI && a.w != kPadI) {
            int ai[4] = {a.x, a.y, a.z, a.w};
            float P[4][3];
            #pragma unroll
            for (int k = 0; k < 4; ++k) {
                int g  = ai[k];
                int gb = g >> 12;
                int gc = cidx[g];
                const float* s = coords + (size_t)(gb * kM + gc) * 3;
                P[k][0] = s[0]; P[k][1] = s[1]; P[k][2] = s[2];
            }
            float b1x = P[1][0] - P[0][0], b1y = P[1][1] - P[0][1], b1z = P[1][2] - P[0][2];
            float b2x = P[2][0] - P[1][0], b2y = P[2][1] - P[1][1], b2z = P[2][2] - P[1][2];
            float b3x = P[3][0] - P[2][0], b3y = P[3][1] - P[2][1], b3z = P[3][2] - P[2][2];
            float n1x = b1y * b2z - b1z * b2y;
            float n1y = b1z * b2x - b1x * b2z;
            float n1z = b1x * b2y - b1y * b2x;
            float n2x = b2y * b3z - b2z * b3y;
            float n2y = b2z * b3x - b2x * b3z;
            float n2z = b2x * b3y - b2y * b3x;
            float nb2 = sqrtf(b2x * b2x + b2y * b2y + b2z * b2z) + 1e-12f;
            float inv = 1.0f / nb2;
            float ux = b2x * inv, uy = b2y * inv, uz = b2z * inv;
            float m1x = n1y * uz - n1z * uy;
            float m1y = n1z * ux - n1x * uz;
            float m1z = n1x * uy - n1y * ux;
            float x = n1x * n2x + n1y * n2y + n1z * n2z;
            float y = m1x * n2x + m1y * n2y + m1z * n2z;
            ang = atan2f(y, x);
        }
        out[(size_t)i * 8 + 0] = ang;
    } else if (role == 2) {
        float o2, o3, o4;
        int p0 = partners[2 * i + 0];
        if (p0 == kPadI) { o2 = o3 = o4 = kPadF; }
        else {
            const float* s = coords + (size_t)(b * kM + p0) * 3;
            o2 = s[0]; o3 = s[1]; o4 = s[2];
        }
        float* o = out + (size_t)i * 8;
        o[2] = o2; o[3] = o3; o[4] = o4;
    } else {
        float o5, o6, o7;
        int p1 = partners[2 * i + 1];
        if (p1 == kPadI) { o5 = o6 = o7 = kPadF; }
        else {
            const float* s = coords + (size_t)(b * kM + p1) * 3;
            o5 = s[0]; o6 = s[1]; o7 = s[2];
        }
        float* o = out + (size_t)i * 8;
        o[5] = o5; o[6] = o6; o[7] = o7;
    }
}

// ---------------------------------------------------------------------------
// Kernel 2 (R15 config): CELL-LIST nbr sums. Task = (row i, neighbor cell k);
// 27*16K = 442K independent tasks (max TLP — the R17 lesson: serializing
// cells per lane regressed 6 µs). k = task>>14, i = task&16383. Consecutive
// lanes = consecutive rows -> coalesced ws reads, 64-address L2 atomics.
// Per-candidate numerics identical to R13/R14/R15 (gram d2 via
// fma(-2,dot,sqi+sqj), exact d2<=49 mask, v_sqrt(|d2|)); only summation
// order differs (positive terms, ~1e-5 vs threshold 20).
// Pads never binned; pad rows return early (col1 = 0 from per_atom).
// ---------------------------------------------------------------------------
__global__ __launch_bounds__(256)
void nbr_cell_kernel(const float4* __restrict__ ws,      // (N,) x,y,z,sq
                     const int*    __restrict__ cellCnt, // (B*1331,)
                     const float4* __restrict__ cells,   // (B*1331*kCap,)
                     float*        __restrict__ out)     // (N,8)
{
    int task = blockIdx.x * 256 + threadIdx.x;
    if (task >= 27 * kN) return;
    int k = task >> 14;            // 0..26  (kN = 16384 = 2^14)
    int i = task & (kN - 1);

    float4 ri = ws[i];
    if (ri.x == kPadF) return;

    int b  = i >> 12;
    int nx = cell_coord(ri.x) + (k / 9)       - 1;
    int ny = cell_coord(ri.y) + ((k / 3) % 3) - 1;
    int nz = cell_coord(ri.z) + (k % 3)       - 1;
    if ((unsigned)nx >= kNC || (unsigned)ny >= kNC || (unsigned)nz >= kNC)
        return;

    int cid = ((b * kNC + nx) * kNC + ny) * kNC + nz;
    int cnt = min(cellCnt[cid], kCap);
    const float4* cp = cells + (size_t)cid * kCap;

    float sum = 0.0f;
    for (int s = 0; s < cnt; ++s) {
        float4 c   = cp[s];
        float dot  = __fmaf_rn(ri.z, c.z,
                     __fmaf_rn(ri.y, c.y, __fmul_rn(ri.x, c.x)));
        float d2   = __fmaf_rn(-2.0f, dot, __fadd_rn(ri.w, c.w));
        float dist = fast_sqrt(__builtin_fabsf(d2));
        sum += (d2 <= 49.0f) ? dist : 0.0f;
    }
    if (sum != 0.0f) {
        atomicAdd(out + (size_t)i * 8 + 1, sum);
    }
}

// ---------------------------------------------------------------------------
// Fallbacks (ws too small): monolithic per-atom + LDS-staged O(M^2) nbr.
// ---------------------------------------------------------------------------
__global__ __launch_bounds__(64)
void per_atom_mono_kernel(const float* __restrict__ coords,
                          const int*   __restrict__ cidx,
                          const int*   __restrict__ partners,
                          const int*   __restrict__ aidx,
                          float*       __restrict__ out)
{
    int i = blockIdx.x * 64 + threadIdx.x;
    if (i >= kN) return;
    int b = i >> 12;

    float o2, o3, o4, o5, o6, o7;
    int p0 = partners[2 * i + 0];
    int p1 = partners[2 * i + 1];
    if (p0 == kPadI) { o2 = o3 = o4 = kPadF; }
    else {
        const float* s = coords + (size_t)(b * kM + p0) * 3;
        o2 = s[0]; o3 = s[1]; o4 = s[2];
    }
    if (p1 == kPadI) { o5 = o6 = o7 = kPadF; }
    else {
        const float* s = coords + (size_t)(b * kM + p1) * 3;
        o5 = s[0]; o6 = s[1]; o7 = s[2];
    }

    int4 a = *reinterpret_cast<const int4*>(aidx + 4 * i);
    float ang = kPadF;
    if (a.x != kPadI && a.y != kPadI && a.z != kPadI && a.w != kPadI) {
        int ai[4] = {a.x, a.y, a.z, a.w};
        float P[4][3];
        #pragma unroll
        for (int k = 0; k < 4; ++k) {
            int g  = ai[k];
            int gb = g >> 12;
            int gc = cidx[g];
            const float* s = coords + (size_t)(gb * kM + gc) * 3;
            P[k][0] = s[0]; P[k][1] = s[1]; P[k][2] = s[2];
        }
        float b1x = P[1][0] - P[0][0], b1y = P[1][1] - P[0][1], b1z = P[1][2] - P[0][2];
        float b2x = P[2][0] - P[1][0], b2y = P[2][1] - P[1][1], b2z = P[2][2] - P[1][2];
        float b3x = P[3][0] - P[2][0], b3y = P[3][1] - P[2][1], b3z = P[3][2] - P[2][2];
        float n1x = b1y * b2z - b1z * b2y;
        float n1y = b1z * b2x - b1x * b2z;
        float n1z = b1x * b2y - b1y * b2x;
        float n2x = b2y * b3z - b2z * b3y;
        float n2y = b2z * b3x - b2x * b3z;
        float n2z = b2x * b3y - b2y * b3x;
        float nb2 = sqrtf(b2x * b2x + b2y * b2y + b2z * b2z) + 1e-12f;
        float inv = 1.0f / nb2;
        float ux = b2x * inv, uy = b2y * inv, uz = b2z * inv;
        float m1x = n1y * uz - n1z * uy;
        float m1y = n1z * ux - n1x * uz;
        float m1z = n1x * uy - n1y * ux;
        float x = n1x * n2x + n1y * n2y + n1z * n2z;
        float y = m1x * n2x + m1y * n2y + m1z * n2z;
        ang = atan2f(y, x);
    }

    float4* o = reinterpret_cast<float4*>(out + (size_t)i * 8);
    o[0] = make_float4(ang, 0.0f, o2, o3);
    o[1] = make_float4(o4, o5, o6, o7);
}

__global__ __launch_bounds__(256)
void nbr_kernel_lds(const float* __restrict__ coords,
                    const int*   __restrict__ cidx,
                    float*       __restrict__ out)
{
    __shared__ float4 sc[kM];
    int b    = blockIdx.x >> 6;
    int row0 = (blockIdx.x & 63) << 6;
    for (int j = threadIdx.x; j < kM; j += 256) {
        int idx = cidx[b * kM + j];
        const float* s = coords + (size_t)(b * kM + idx) * 3;
        float x = s[0], y = s[1], z = s[2];
        sc[j] = make_float4(x, y, z, sq_np(x, y, z));
    }
    __syncthreads();
    int r   = row0 + (threadIdx.x >> 2);
    int sub = threadIdx.x & 3;
    float4 ci = sc[r];
    float sum = 0.0f;
    for (int jj = 0; jj < kM / 4; ++jj) {
        float4 c   = sc[4 * jj + sub];
        float dot  = __fmaf_rn(ci.z, c.z,
                     __fmaf_rn(ci.y, c.y, __fmul_rn(ci.x, c.x)));
        float d2   = __fmaf_rn(-2.0f, dot, __fadd_rn(ci.w, c.w));
        float dist = fast_sqrt(fmaxf(d2, 0.0f));
        sum += (d2 <= 49.0f) ? dist : 0.0f;
    }
    sum += __shfl_xor(sum, 1);
    sum += __shfl_xor(sum, 2);
    if (sub == 0)
        out[(size_t)(b * kM + r) * 8 + 1] = (ci.x != kPadF) ? sum : 0.0f;
}

// ---------------------------------------------------------------------------
extern "C" void kernel_launch(void* const* d_in, const int* in_sizes, int n_in,
                              void* d_out, int out_size, void* d_ws, size_t ws_size,
                              hipStream_t stream) {
    const float* coords   = (const float*)d_in[0];
    const int*   cidx     = (const int*)d_in[2];
    const int*   partners = (const int*)d_in[3];
    const int*   aidx     = (const int*)d_in[4];
    float*       out      = (float*)d_out;

    char*   wsB     = (char*)d_ws;
    float4* ws      = (float4*)(wsB + kOffWs);
    int*    cellCnt = (int*)(wsB + kOffCnt);
    float4* cells   = (float4*)(wsB + kOffCells);

    if (ws_size >= kWsNeeded) {
        hipMemsetAsync(cellCnt, 0, (size_t)kB * kNC3 * sizeof(int), stream);
        hipLaunchKernelGGL(per_atom_kernel, dim3(256), dim3(256), 0, stream,
                           coords, cidx, partners, aidx, out, ws, cellCnt, cells);
        hipLaunchKernelGGL(nbr_cell_kernel, dim3((27 * kN) / 256), dim3(256),
                           0, stream, ws, cellCnt, cells, out);
    } else {
        hipLaunchKernelGGL(per_atom_mono_kernel, dim3(kN / 64), dim3(64), 0, stream,
                           coords, cidx, partners, aidx, out);
        hipLaunchKernelGGL(nbr_kernel_lds, dim3(kB * 64), dim3(256), 0, stream,
                           coords, cidx, out);
    }
}